// Round 12
// baseline (123.188 us; speedup 1.0000x reference)
//
#include <hip/hip_runtime.h>
#include <hip/hip_bf16.h>

typedef unsigned short ushort_t;
typedef unsigned int uint_t;
typedef __attribute__((ext_vector_type(8))) short short8;
typedef __attribute__((ext_vector_type(4))) float f32x4;
typedef __attribute__((ext_vector_type(2))) uint_t uint2_t;

#define FOLD 128
// exp(COEFF*x^2) = 2^(-(x*S)^2);  S = sqrt(0.5/ln2)/DELTA, DELTA = 30/63
#define S_CONST 1.78357580f
#define DS_CONST 0.84932180f   /* DELTA * S_CONST = sqrt(0.5/ln2) */

__device__ __forceinline__ uint_t pkbf(float a, float b) {
    // dword = bf16(b)<<16 | bf16(a), RNE via v_cvt_pk_bf16_f32 (1 inst).
    __hip_bfloat162 h2 = __float22bfloat162_rn(float2{a, b});
    uint_t u;
    __builtin_memcpy(&u, &h2, sizeof(u));
    return u;
}

// LDS-only barrier: drains ds ops (lgkmcnt) but lets global loads/stores stay
// in flight across the barrier.
__device__ __forceinline__ void softbar() {
    asm volatile("s_waitcnt lgkmcnt(0)" ::: "memory");
    __builtin_amdgcn_s_barrier();
    asm volatile("" ::: "memory");
}

#define TEDGE 32

// 512 threads = 8 waves; wave w owns output channels [w*16, w*16+16).
// W fragments built in-block from fp32 W (no separate pack kernel).
__global__ __launch_bounds__(512, 4) void fused(
    const float* __restrict__ lig,
    const float* __restrict__ p0, const float* __restrict__ p1,
    const float* __restrict__ p2, const float* __restrict__ p3,
    const float* __restrict__ p4,
    const float* __restrict__ W1, const float* __restrict__ W2,
    const float* __restrict__ b1, const float* __restrict__ b2,
    const int* __restrict__ src, const int* __restrict__ dst,
    float* __restrict__ out, int E)
{
    __shared__ float d_lds[2][5][TEDGE];
    __shared__ alignas(16) uint_t attrU[TEDGE * 160];  // [32 e][320 k] bf16 dwords, XOR-swizzled
    __shared__ alignas(16) uint_t h_u[TEDGE * 64];     // h^T: [32 e][128 ch] bf16 dwords, XOR-swizzled
    __shared__ alignas(16) float out_s[TEDGE * FOLD];  // staged fp32 out tile, XOR-swizzled

    const int t = threadIdx.x;
    const int w = t >> 6;        // wave 0..7: channels [w*16, w*16+16)
    const int l = t & 63;
    const int lrow = l & 15, lgrp = l >> 4;
    const int aswz = (lrow & 7) << 2;
    const int ntiles = (E + TEDGE - 1) / TEDGE;
    const int G = gridDim.x;

    // ---- Build per-wave W fragments from fp32 weights (once per block).
    // wb1[ks] elem j = bf16(W1[ks*32 + lgrp*8 + j][w*16 + lrow]); same for wb2/W2.
    short8 wb1[10], wb2[4];
    #pragma unroll
    for (int ks = 0; ks < 10; ++ks) {
        uint_t dwv[4];
        #pragma unroll
        for (int jj = 0; jj < 4; ++jj) {
            float wa = W1[(ks * 32 + lgrp * 8 + 2 * jj)     * FOLD + w * 16 + lrow];
            float wc = W1[(ks * 32 + lgrp * 8 + 2 * jj + 1) * FOLD + w * 16 + lrow];
            dwv[jj] = pkbf(wa, wc);
        }
        __builtin_memcpy(&wb1[ks], dwv, 16);
    }
    #pragma unroll
    for (int ks = 0; ks < 4; ++ks) {
        uint_t dwv[4];
        #pragma unroll
        for (int jj = 0; jj < 4; ++jj) {
            float wa = W2[(ks * 32 + lgrp * 8 + 2 * jj)     * FOLD + w * 16 + lrow];
            float wc = W2[(ks * 32 + lgrp * 8 + 2 * jj + 1) * FOLD + w * 16 + lrow];
            dwv[jj] = pkbf(wa, wc);
        }
        __builtin_memcpy(&wb2[ks], dwv, 16);
    }
    f32x4 hb1 = *reinterpret_cast<const f32x4*>(&b1[w * 16 + lgrp * 4]);
    f32x4 hb2 = *reinterpret_cast<const f32x4*>(&b2[w * 16 + lgrp * 4]);

    // gather mapping: 160 threads, unit = (channel g1c, edge g1m)
    const bool gth = (t < 160);
    const int g1c = t >> 5, g1m = t & 31;
    const float* GP = (g1c == 0) ? p0 : (g1c == 1) ? p1 : (g1c == 2) ? p2 : (g1c == 3) ? p3 : p4;

    // exp mapping: edge m2 = t>>4 (0..31), k-quad q2 = t&15
    const int m2 = t >> 4, q2 = t & 15;
    const int swz = (m2 & 7) << 2;
    const float ubase = (float)(4 * q2) * DS_CONST;

    int tile = blockIdx.x;
    if (tile >= ntiles) return;

    // ---- Prologue: gather tile 0 (synchronous) ----
    if (gth) {
        int e = tile * TEDGE + g1m; if (e >= E) e = E - 1;
        int s = src[e], dd = dst[e];
        float dx = lig[3 * s]     - GP[3 * dd];
        float dy = lig[3 * s + 1] - GP[3 * dd + 1];
        float dz = lig[3 * s + 2] - GP[3 * dd + 2];
        d_lds[0][g1c][g1m] = sqrtf(dx * dx + dy * dy + dz * dz);
    }
    // ---- Prefetch src/dst indices for tile+G (depth-2 pipeline head) ----
    int sN = 0, dN = 0;
    if (gth && tile + G < ntiles) {
        int e = (tile + G) * TEDGE + g1m; if (e >= E) e = E - 1;
        sN = src[e]; dN = dst[e];
    }
    softbar();

    int buf = 0;
    while (true) {
        const int next = tile + G;
        const bool havenext = (next < ntiles);

        // ---- Issue next tile's position loads (indices already resident) ----
        float ax, ay, az, bx, by, bz;
        if (gth && havenext) {
            ax = lig[3 * sN];     bx = GP[3 * dN];
            ay = lig[3 * sN + 1]; by = GP[3 * dN + 1];
            az = lig[3 * sN + 2]; bz = GP[3 * dN + 2];
        }
        // ---- Issue src/dst for tile+2G ----
        int sN2 = sN, dN2 = dN;
        if (gth && next + G < ntiles) {
            int e = (next + G) * TEDGE + g1m; if (e >= E) e = E - 1;
            sN2 = src[e]; dN2 = dst[e];
        }

        // ---- Phase 2: RBF expansion -> attrU (1 edge x 4 k per channel per thread) ----
        {
            float dv[5];
            #pragma unroll
            for (int c = 0; c < 5; ++c) dv[c] = d_lds[buf][c][m2];
            #pragma unroll
            for (int c = 0; c < 5; ++c) {
                float u0 = __builtin_fmaf(dv[c], S_CONST, -ubase);
                float u1 = u0 - DS_CONST;
                float u2 = u0 - 2.0f * DS_CONST;
                float u3 = u0 - 3.0f * DS_CONST;
                float v0 = __builtin_amdgcn_exp2f(-(u0 * u0));
                float v1 = __builtin_amdgcn_exp2f(-(u1 * u1));
                float v2 = __builtin_amdgcn_exp2f(-(u2 * u2));
                float v3 = __builtin_amdgcn_exp2f(-(u3 * u3));
                uint2_t pv;
                pv[0] = pkbf(v0, v1);
                pv[1] = pkbf(v2, v3);
                int o = 32 * c + 2 * q2;
                *reinterpret_cast<uint2_t*>(&attrU[m2 * 160 + (o ^ swz)]) = pv;
            }
        }
        softbar();   // A — gather loads for next tile remain in flight

        // ---- Phase 3 (swapped): g1 = (attr@W1)^T slice; D: row=channel, col=edge ----
        f32x4 g1[2] = {{0.f,0.f,0.f,0.f},{0.f,0.f,0.f,0.f}};   // [ehalf]
        #pragma unroll
        for (int ks = 0; ks < 10; ++ks) {
            int o = ks * 16 + lgrp * 4;
            short8 af0 = *reinterpret_cast<const short8*>(&attrU[lrow * 160 + (o ^ aswz)]);
            short8 af1 = *reinterpret_cast<const short8*>(&attrU[(lrow + 16) * 160 + (o ^ aswz)]);
            g1[0] = __builtin_amdgcn_mfma_f32_16x16x32_bf16(wb1[ks], af0, g1[0], 0, 0, 0);
            g1[1] = __builtin_amdgcn_mfma_f32_16x16x32_bf16(wb1[ks], af1, g1[1], 0, 0, 0);
        }

        // bias + relu + pack h^T: lane holds 4 consecutive channels of edge (eh*16+lrow)
        #pragma unroll
        for (int eh = 0; eh < 2; ++eh) {
            float v0 = fmaxf(g1[eh][0] + hb1[0], 0.f);
            float v1 = fmaxf(g1[eh][1] + hb1[1], 0.f);
            float v2 = fmaxf(g1[eh][2] + hb1[2], 0.f);
            float v3 = fmaxf(g1[eh][3] + hb1[3], 0.f);
            uint2_t pv;
            pv[0] = pkbf(v0, v1);
            pv[1] = pkbf(v2, v3);
            int e = eh * 16 + lrow;
            int dw = (w * 8 + lgrp * 2) ^ ((e & 7) << 2);
            *reinterpret_cast<uint2_t*>(&h_u[e * 64 + dw]) = pv;
        }

        // ---- Consume prefetched gathers LATE ----
        if (gth && havenext) {
            float dx = ax - bx, dy = ay - by, dz = az - bz;
            d_lds[buf ^ 1][g1c][g1m] = sqrtf(dx * dx + dy * dy + dz * dz);
        }
        sN = sN2; dN = dN2;
        softbar();   // B

        // ---- Phase 4 (swapped): o2 = (h@W2)^T slice ----
        f32x4 o2[2] = {{0.f,0.f,0.f,0.f},{0.f,0.f,0.f,0.f}};
        #pragma unroll
        for (int ks = 0; ks < 4; ++ks) {
            int dw = ks * 16 + lgrp * 4;
            short8 hf0 = *reinterpret_cast<const short8*>(&h_u[lrow * 64 + (dw ^ aswz)]);
            short8 hf1 = *reinterpret_cast<const short8*>(&h_u[(lrow + 16) * 64 + (dw ^ aswz)]);
            o2[0] = __builtin_amdgcn_mfma_f32_16x16x32_bf16(wb2[ks], hf0, o2[0], 0, 0, 0);
            o2[1] = __builtin_amdgcn_mfma_f32_16x16x32_bf16(wb2[ks], hf1, o2[1], 0, 0, 0);
        }

        // ---- Phase 5a: bias + stage fp32 tile to LDS (XOR-swizzled, conflict-free) ----
        #pragma unroll
        for (int eh = 0; eh < 2; ++eh) {
            int e = eh * 16 + lrow;
            f32x4 v = o2[eh] + hb2;
            int ch4 = w * 4 + lgrp;                       // 4-dword group index 0..31
            *reinterpret_cast<f32x4*>(&out_s[e * FOLD + ((ch4 ^ (e & 7)) << 2)]) = v;
        }
        softbar();   // C

        // ---- Phase 5b: fully-coalesced NT stores (512 thr x 32B = 16 KB contiguous) ----
        {
            int e_loc = t >> 4;
            if (tile * TEDGE + e_loc < E) {
                float* dp = out + (size_t)tile * TEDGE * FOLD + t * 8;
                #pragma unroll
                for (int k = 0; k < 2; ++k) {
                    int ch4 = (t & 15) * 2 + k;
                    f32x4 v = *reinterpret_cast<const f32x4*>(
                        &out_s[e_loc * FOLD + ((ch4 ^ (e_loc & 7)) << 2)]);
                    __builtin_nontemporal_store(v, reinterpret_cast<f32x4*>(dp) + k);
                }
            }
        }

        if (!havenext) break;
        tile = next;
        buf ^= 1;
    }
}

extern "C" void kernel_launch(void* const* d_in, const int* in_sizes, int n_in,
                              void* d_out, int out_size, void* d_ws, size_t ws_size,
                              hipStream_t stream) {
    const float* lig = (const float*)d_in[0];
    const float* p0  = (const float*)d_in[1];
    const float* p1  = (const float*)d_in[2];
    const float* p2  = (const float*)d_in[3];
    const float* p3  = (const float*)d_in[4];
    const float* p4  = (const float*)d_in[5];
    const float* W1  = (const float*)d_in[6];
    const float* b1  = (const float*)d_in[7];
    const float* W2  = (const float*)d_in[8];
    const float* b2  = (const float*)d_in[9];
    const int* src   = (const int*)d_in[10];
    const int* dst   = (const int*)d_in[11];
    float* out = (float*)d_out;
    const int E = in_sizes[10];

    int tiles = (E + TEDGE - 1) / TEDGE;
    int nblk = tiles < 512 ? tiles : 512;
    fused<<<nblk, 512, 0, stream>>>(lig, p0, p1, p2, p3, p4, W1, W2,
                                    b1, b2, src, dst, out, E);
}

// Round 13
// 109.310 us; speedup vs baseline: 1.1270x; 1.1270x over previous
//
#include <hip/hip_runtime.h>
#include <hip/hip_bf16.h>

typedef unsigned short ushort_t;
typedef unsigned int uint_t;
typedef __attribute__((ext_vector_type(8))) short short8;
typedef __attribute__((ext_vector_type(4))) float f32x4;
typedef __attribute__((ext_vector_type(2))) uint_t uint2_t;

#define FOLD 128
// exp(COEFF*x^2) = 2^(-(x*S)^2);  S = sqrt(0.5/ln2)/DELTA, DELTA = 30/63
#define S_CONST 1.78357580f
#define DS_CONST 0.84932180f   /* DELTA * S_CONST = sqrt(0.5/ln2) */

__device__ __forceinline__ uint_t pkbf(float a, float b) {
    // dword = bf16(b)<<16 | bf16(a), RNE via v_cvt_pk_bf16_f32
    __hip_bfloat162 h2 = __float22bfloat162_rn(float2{a, b});
    uint_t u;
    __builtin_memcpy(&u, &h2, sizeof(u));
    return u;
}

#define NWAVES 8
// dword offsets in dynamic LDS (total 37120 dwords = 145 KB)
#define W1_OFF 0        /* 20480 dw: W1 bf16 fragment-packed */
#define W2_OFF 20480    /*  8192 dw: W2 bf16 fragment-packed */
#define B1_OFF 28672    /*   128 dw fp32 */
#define B2_OFF 28800    /*   128 dw fp32 */
#define H_OFF  28928    /*  8 waves x 1024 dw h-scratch */
#define LDS_DW 37120

// Barrier-free wave-autonomous kernel: one W-staging barrier, then each wave
// processes 32-edge tiles fully independently (no block sync in the loop).
__global__ __launch_bounds__(512) void fused(
    const float* __restrict__ lig,
    const float* __restrict__ p0, const float* __restrict__ p1,
    const float* __restrict__ p2, const float* __restrict__ p3,
    const float* __restrict__ p4,
    const float* __restrict__ W1, const float* __restrict__ W2,
    const float* __restrict__ b1, const float* __restrict__ b2,
    const int* __restrict__ src, const int* __restrict__ dst,
    float* __restrict__ out, int E)
{
    extern __shared__ uint_t smem[];
    uint_t* W1L = smem + W1_OFF;
    uint_t* W2L = smem + W2_OFF;
    const float* b1L = (const float*)(smem + B1_OFF);
    const float* b2L = (const float*)(smem + B2_OFF);

    const int t = threadIdx.x;
    const int w = t >> 6;
    const int l = t & 63;
    const int eL = l & 15, g = l >> 4;
    uint_t* hw = smem + H_OFF + (w << 10);   // 4 KB private scratch per wave

    // ---- Stage W1/W2 (bf16 fragment order) + biases into LDS, once ----
    // frag dword idx = ((ks*8+nt)*64 + l2)*4 + jj  <->  elems j=2jj,2jj+1:
    //   W[ks*32 + (l2>>4)*8 + j][nt*16 + (l2&15)]
    for (int idx = t; idx < 20480; idx += 512) {
        int jj = idx & 3, l2 = (idx >> 2) & 63, nt = (idx >> 8) & 7, ks = idx >> 11;
        int row = ks * 32 + ((l2 >> 4) << 3) + 2 * jj;
        int col = nt * 16 + (l2 & 15);
        W1L[idx] = pkbf(W1[row * FOLD + col], W1[(row + 1) * FOLD + col]);
    }
    for (int idx = t; idx < 8192; idx += 512) {
        int jj = idx & 3, l2 = (idx >> 2) & 63, nt = (idx >> 8) & 7, ks = idx >> 11;
        int row = ks * 32 + ((l2 >> 4) << 3) + 2 * jj;
        int col = nt * 16 + (l2 & 15);
        W2L[idx] = pkbf(W2[row * FOLD + col], W2[(row + 1) * FOLD + col]);
    }
    if (t < 128) ((float*)(smem + B1_OFF))[t] = b1[t];
    else if (t < 256) ((float*)(smem + B2_OFF))[t - 128] = b2[t - 128];
    __syncthreads();   // the ONLY block barrier

    const int NT = (E + 31) >> 5;
    const int stride = gridDim.x * NWAVES;
    int wt = blockIdx.x * NWAVES + w;
    if (wt >= NT) return;

    // lane's gather duty: channel g (0..3) via GP; lanes g==0 also do channel 4 (p4)
    const float* GP = (g == 0) ? p0 : (g == 1) ? p1 : (g == 2) ? p2 : p3;
    const bool g0 = (g == 0);
    const float gbase = (float)(8 * g) * DS_CONST;

    // ---- Prologue: idx + pos loads for first tile (both edge halves) ----
    float Ax[2], Ay[2], Az[2], Px[2], Py[2], Pz[2], Qx[2], Qy[2], Qz[2];
    {
        #pragma unroll
        for (int eh = 0; eh < 2; ++eh) {
            int e = wt * 32 + eh * 16 + eL; if (e >= E) e = E - 1;
            int s = src[e], d2 = dst[e];
            Ax[eh] = lig[3 * s]; Ay[eh] = lig[3 * s + 1]; Az[eh] = lig[3 * s + 2];
            Px[eh] = GP[3 * d2]; Py[eh] = GP[3 * d2 + 1]; Pz[eh] = GP[3 * d2 + 2];
            if (g0) { Qx[eh] = p4[3 * d2]; Qy[eh] = p4[3 * d2 + 1]; Qz[eh] = p4[3 * d2 + 2]; }
        }
    }

    while (true) {
        const int wt2 = wt + stride;
        const bool more = (wt2 < NT);

        // ---- Issue next tile's src/dst loads ----
        int sB[2], dB[2];
        if (more) {
            #pragma unroll
            for (int eh = 0; eh < 2; ++eh) {
                int e = wt2 * 32 + eh * 16 + eL; if (e >= E) e = E - 1;
                sB[eh] = src[e]; dB[eh] = dst[e];
            }
        }

        // ---- Distances + cross-lane redistribution (wave-local shuffles) ----
        float u00[5][2];
        #pragma unroll
        for (int eh = 0; eh < 2; ++eh) {
            float dx = Ax[eh] - Px[eh], dy = Ay[eh] - Py[eh], dz = Az[eh] - Pz[eh];
            float dm = sqrtf(dx * dx + dy * dy + dz * dz);   // channel g of edge eL
            float d4 = 0.f;
            if (g0) {
                float ex = Ax[eh] - Qx[eh], ey = Ay[eh] - Qy[eh], ez = Az[eh] - Qz[eh];
                d4 = sqrtf(ex * ex + ey * ey + ez * ez);
            }
            #pragma unroll
            for (int c = 0; c < 4; ++c)
                u00[c][eh] = __builtin_fmaf(__shfl(dm, c * 16 + eL), S_CONST, -gbase);
            u00[4][eh] = __builtin_fmaf(__shfl(d4, eL), S_CONST, -gbase);
        }

        // ---- RBF expansion into register B-fragments a[eh][ks] ----
        short8 a[2][10];
        #pragma unroll
        for (int ks = 0; ks < 10; ++ks) {
            const int c = ks >> 1;
            #pragma unroll
            for (int eh = 0; eh < 2; ++eh) {
                uint_t dwv[4];
                #pragma unroll
                for (int jj = 0; jj < 4; ++jj) {
                    float k0 = (float)((ks & 1) * 32 + 2 * jj) * DS_CONST;
                    float k1 = (float)((ks & 1) * 32 + 2 * jj + 1) * DS_CONST;
                    float ua = u00[c][eh] - k0;
                    float ub = u00[c][eh] - k1;
                    float va = __builtin_amdgcn_exp2f(-(ua * ua));
                    float vb = __builtin_amdgcn_exp2f(-(ub * ub));
                    dwv[jj] = pkbf(va, vb);
                }
                __builtin_memcpy(&a[eh][ks], dwv, 16);
            }
        }

        // ---- Issue next tile's position loads (indices arrived during exp) ----
        float Bx[2], By[2], Bz[2], Rx[2], Ry[2], Rz[2], Sx[2], Sy[2], Sz[2];
        if (more) {
            #pragma unroll
            for (int eh = 0; eh < 2; ++eh) {
                Bx[eh] = lig[3 * sB[eh]]; By[eh] = lig[3 * sB[eh] + 1]; Bz[eh] = lig[3 * sB[eh] + 2];
                Rx[eh] = GP[3 * dB[eh]]; Ry[eh] = GP[3 * dB[eh] + 1]; Rz[eh] = GP[3 * dB[eh] + 2];
                if (g0) { Sx[eh] = p4[3 * dB[eh]]; Sy[eh] = p4[3 * dB[eh] + 1]; Sz[eh] = p4[3 * dB[eh] + 2]; }
            }
        }

        // ---- GEMM1: acc1[nt][eh] = (W1^T-chunk)·attr; each W-frag read once ----
        f32x4 acc1[8][2];
        #pragma unroll
        for (int nt = 0; nt < 8; ++nt)
            #pragma unroll
            for (int eh = 0; eh < 2; ++eh) acc1[nt][eh] = f32x4{0.f, 0.f, 0.f, 0.f};
        #pragma unroll
        for (int ks = 0; ks < 10; ++ks) {
            #pragma unroll
            for (int nt = 0; nt < 8; ++nt) {
                const short8 wf = *reinterpret_cast<const short8*>(&W1L[((ks * 8 + nt) * 64 + l) * 4]);
                acc1[nt][0] = __builtin_amdgcn_mfma_f32_16x16x32_bf16(wf, a[0][ks], acc1[nt][0], 0, 0, 0);
                acc1[nt][1] = __builtin_amdgcn_mfma_f32_16x16x32_bf16(wf, a[1][ks], acc1[nt][1], 0, 0, 0);
            }
        }

        // ---- Per edge-half: h round-trip through private scratch, GEMM2, store ----
        const int swzE = (eL & 7) << 3;
        #pragma unroll
        for (int eh = 0; eh < 2; ++eh) {
            // bias + relu + pack h (lane: 4 ch of edge eL per nt)
            #pragma unroll
            for (int nt = 0; nt < 8; ++nt) {
                f32x4 bv = *reinterpret_cast<const f32x4*>(&b1L[nt * 16 + g * 4]);
                float v0 = fmaxf(acc1[nt][eh][0] + bv[0], 0.f);
                float v1 = fmaxf(acc1[nt][eh][1] + bv[1], 0.f);
                float v2 = fmaxf(acc1[nt][eh][2] + bv[2], 0.f);
                float v3 = fmaxf(acc1[nt][eh][3] + bv[3], 0.f);
                uint2_t pv;
                pv[0] = pkbf(v0, v1);
                pv[1] = pkbf(v2, v3);
                *reinterpret_cast<uint2_t*>(&hw[eL * 64 + ((nt * 8 + g * 2) ^ swzE)]) = pv;
            }
            // GEMM2 from scratch (wave-local; compiler orders ds ops via lgkmcnt)
            f32x4 acc2[8];
            #pragma unroll
            for (int nt = 0; nt < 8; ++nt) acc2[nt] = f32x4{0.f, 0.f, 0.f, 0.f};
            #pragma unroll
            for (int ks2 = 0; ks2 < 4; ++ks2) {
                const short8 hf = *reinterpret_cast<const short8*>(&hw[eL * 64 + ((ks2 * 16 + g * 4) ^ swzE)]);
                #pragma unroll
                for (int nt = 0; nt < 8; ++nt) {
                    const short8 wf2 = *reinterpret_cast<const short8*>(&W2L[((ks2 * 8 + nt) * 64 + l) * 4]);
                    acc2[nt] = __builtin_amdgcn_mfma_f32_16x16x32_bf16(wf2, hf, acc2[nt], 0, 0, 0);
                }
            }
            // stores
            int e = wt * 32 + eh * 16 + eL;
            if (e < E) {
                #pragma unroll
                for (int nt = 0; nt < 8; ++nt) {
                    f32x4 bv2 = *reinterpret_cast<const f32x4*>(&b2L[nt * 16 + g * 4]);
                    f32x4 v = acc2[nt] + bv2;
                    __builtin_nontemporal_store(v,
                        reinterpret_cast<f32x4*>(&out[(size_t)e * FOLD + nt * 16 + g * 4]));
                }
            }
            // drain this half's LDS ops before overwriting scratch
            asm volatile("s_waitcnt lgkmcnt(0)" ::: "memory");
        }

        if (!more) break;
        wt = wt2;
        #pragma unroll
        for (int eh = 0; eh < 2; ++eh) {
            Ax[eh] = Bx[eh]; Ay[eh] = By[eh]; Az[eh] = Bz[eh];
            Px[eh] = Rx[eh]; Py[eh] = Ry[eh]; Pz[eh] = Rz[eh];
            if (g0) { Qx[eh] = Sx[eh]; Qy[eh] = Sy[eh]; Qz[eh] = Sz[eh]; }
        }
    }
}

extern "C" void kernel_launch(void* const* d_in, const int* in_sizes, int n_in,
                              void* d_out, int out_size, void* d_ws, size_t ws_size,
                              hipStream_t stream) {
    const float* lig = (const float*)d_in[0];
    const float* p0  = (const float*)d_in[1];
    const float* p1  = (const float*)d_in[2];
    const float* p2  = (const float*)d_in[3];
    const float* p3  = (const float*)d_in[4];
    const float* p4  = (const float*)d_in[5];
    const float* W1  = (const float*)d_in[6];
    const float* b1  = (const float*)d_in[7];
    const float* W2  = (const float*)d_in[8];
    const float* b2  = (const float*)d_in[9];
    const int* src   = (const int*)d_in[10];
    const int* dst   = (const int*)d_in[11];
    float* out = (float*)d_out;
    const int E = in_sizes[10];

    hipFuncSetAttribute(reinterpret_cast<const void*>(fused),
                        hipFuncAttributeMaxDynamicSharedMemorySize, LDS_DW * 4);

    int nblk = 256;   // 1 block/CU (145 KB LDS); 8 autonomous waves per block
    fused<<<nblk, 512, LDS_DW * 4, stream>>>(lig, p0, p1, p2, p3, p4, W1, W2,
                                             b1, b2, src, dst, out, E);
}